// Round 1
// baseline (413.468 us; speedup 1.0000x reference)
//
#include <hip/hip_runtime.h>

// Compact Bilinear Pooling, reformulated:
//   y_b[d] = sum_{i,j} w1[i] w2[j] (X_b X_b^T)[i,j] [ (h1[i]+h2[j]) % D == d ]
// i.e. per-batch Gram GEMM (MFMA, split-bf16 for fp32-like accuracy) fused with
// a count-sketch scatter into a 16384-bin LDS histogram, then signed-sqrt + L2 norm.

#define D_PROJ 16384
#define C_CH   2048
#define HW_N   196
#define B_N    16
#define RI     64      // i-rows per block (16 per wave)
#define THREADS 256

typedef short  short8 __attribute__((ext_vector_type(8)));
typedef float  f32x4  __attribute__((ext_vector_type(4)));

static __device__ inline unsigned short f2bf(float f) {
    union { float f; unsigned u; } a; a.f = f;
    unsigned u = a.u;
    return (unsigned short)((u + 0x7FFFu + ((u >> 16) & 1u)) >> 16);  // RNE
}
static __device__ inline float bf2f(unsigned short h) {
    union { unsigned u; float f; } a; a.u = ((unsigned)h) << 16;
    return a.f;
}
// split fp32 -> bf16 hi + bf16 lo (hi RNE, lo captures residual)
static __device__ inline void cvt_split(const float (&v)[8], short8& hi, short8& lo) {
#pragma unroll
    for (int e = 0; e < 8; ++e) {
        unsigned short h = f2bf(v[e]);
        hi[e] = (short)h;
        lo[e] = (short)f2bf(v[e] - bf2f(h));
    }
}

static __device__ inline f32x4 mfma16(short8 a, short8 b, f32x4 c) {
    return __builtin_amdgcn_mfma_f32_16x16x32_bf16(a, b, c, 0, 0, 0);
}

__global__ __launch_bounds__(THREADS, 2)
void cbp_gram_scatter(const float* __restrict__ x,
                      const float* __restrict__ w1f,
                      const float* __restrict__ w2f,
                      const int*   __restrict__ h1,
                      const int*   __restrict__ h2,
                      float*       __restrict__ y) {
    __shared__ float hist[D_PROJ];          // 64 KB -> 2 blocks/CU

    const int b    = blockIdx.y;
    const int i0   = blockIdx.x * RI;
    const int tid  = threadIdx.x;
    const int wave = tid >> 6;              // 0..3, owns rows i0+16w..+15
    const int lane = tid & 63;
    const int l15  = lane & 15;
    const int lgrp = lane >> 4;             // 0..3 (k-slice group)

    for (int t = tid; t < D_PROJ; t += THREADS) hist[t] = 0.0f;

    const float* xb = x + (size_t)b * (C_CH * HW_N);

    // ---- preload A fragments: 16 rows/wave, K padded 196->224 (7 steps of 32) ----
    // A-frag lane layout: row = lane&15, k = (lane>>4)*8 + e  (k-perm cancels vs B)
    const int    irow = i0 + wave * 16 + l15;
    const float* xa   = xb + (size_t)irow * HW_N;
    const float  w1s  = w1f[irow];          // fold w1 into A rows (exact, +-1)
    short8 a_hi[7], a_lo[7];
#pragma unroll
    for (int ks = 0; ks < 7; ++ks) {
        const int k0 = ks * 32 + lgrp * 8;
        float v[8];
#pragma unroll
        for (int e = 0; e < 8; ++e) {
            const int k = k0 + e;
            v[e] = (k < HW_N) ? xa[k] * w1s : 0.0f;
        }
        cvt_split(v, a_hi[ks], a_lo[ks]);
    }

    // scatter metadata for this lane's 4 C-rows: row = lgrp*4 + r
    int bin1[4];
#pragma unroll
    for (int r = 0; r < 4; ++r) bin1[r] = h1[i0 + wave * 16 + lgrp * 4 + r];

    __syncthreads();                        // hist zeroed before any atomics

    // ---- loop over all j-tiles of 16 columns ----
    for (int jt = 0; jt < C_CH / 16; ++jt) {
        const int    j0   = jt * 16;
        const int    jrow = j0 + l15;
        const float* xj   = xb + (size_t)jrow * HW_N;
        const float  w2s  = w2f[jrow];      // fold w2 into B cols (exact, +-1)
        const int    h2j  = h2[jrow];

        f32x4 acc0 = {0.f, 0.f, 0.f, 0.f};
        f32x4 acc1 = {0.f, 0.f, 0.f, 0.f};
#pragma unroll
        for (int ks = 0; ks < 7; ++ks) {
            const int k0 = ks * 32 + lgrp * 8;
            float v[8];
            if (ks < 6) {                   // rows are 196 floats: 16B-aligned slices
                f32x4 p0 = *(const f32x4*)(xj + k0);
                f32x4 p1 = *(const f32x4*)(xj + k0 + 4);
#pragma unroll
                for (int e = 0; e < 4; ++e) { v[e] = p0[e]; v[4 + e] = p1[e]; }
            } else {                        // K tail: 192..195 valid, rest zero
#pragma unroll
                for (int e = 0; e < 8; ++e) {
                    const int k = k0 + e;
                    v[e] = (k < HW_N) ? xj[k] : 0.0f;
                }
            }
#pragma unroll
            for (int e = 0; e < 8; ++e) v[e] *= w2s;
            short8 bhi, blo;
            cvt_split(v, bhi, blo);
            // split-bf16: G = hi*hi + hi*lo + lo*hi  (lo*lo ~2^-18, dropped)
            if (ks & 1) {
                acc1 = mfma16(a_hi[ks], bhi, acc1);
                acc1 = mfma16(a_hi[ks], blo, acc1);
                acc1 = mfma16(a_lo[ks], bhi, acc1);
            } else {
                acc0 = mfma16(a_hi[ks], bhi, acc0);
                acc0 = mfma16(a_hi[ks], blo, acc0);
                acc0 = mfma16(a_lo[ks], bhi, acc0);
            }
        }
        const f32x4 g = acc0 + acc1;
        // C/D layout (HW-verified): col = lane&15 -> j, row = (lane>>4)*4+r -> i
#pragma unroll
        for (int r = 0; r < 4; ++r) {
            int bin = bin1[r] + h2j;
            if (bin >= D_PROJ) bin -= D_PROJ;
            atomicAdd(&hist[bin], g[r]);
        }
    }

    __syncthreads();
    float* yb = y + (size_t)b * D_PROJ;
    for (int t = tid; t < D_PROJ; t += THREADS)
        atomicAdd(&yb[t], hist[t]);
}

__global__ void cbp_finalize(float* __restrict__ y) {
    const int b   = blockIdx.x;
    const int tid = threadIdx.x;
    float* yb = y + (size_t)b * D_PROJ;
    __shared__ float partial[4];

    float ssum = 0.f;
    for (int t = tid; t < D_PROJ; t += 256) {
        float v = yb[t];
        float s = copysignf(sqrtf(fabsf(v) + 1e-8f), v);
        yb[t] = s;
        ssum += s * s;
    }
    const int lane = tid & 63, wv = tid >> 6;
#pragma unroll
    for (int off = 32; off > 0; off >>= 1) ssum += __shfl_down(ssum, off, 64);
    if (lane == 0) partial[wv] = ssum;
    __syncthreads();
    const float total = partial[0] + partial[1] + partial[2] + partial[3];
    const float inv = 1.0f / sqrtf(total + 1e-8f);
    for (int t = tid; t < D_PROJ; t += 256) yb[t] *= inv;
}

extern "C" void kernel_launch(void* const* d_in, const int* in_sizes, int n_in,
                              void* d_out, int out_size, void* d_ws, size_t ws_size,
                              hipStream_t stream) {
    const float* x  = (const float*)d_in[0];
    const float* w1 = (const float*)d_in[1];
    const float* w2 = (const float*)d_in[2];
    const int*   h1 = (const int*)d_in[3];
    const int*   h2 = (const int*)d_in[4];
    float* y = (float*)d_out;

    hipMemsetAsync(y, 0, (size_t)B_N * D_PROJ * sizeof(float), stream);

    dim3 grid(C_CH / RI, B_N);
    cbp_gram_scatter<<<grid, THREADS, 0, stream>>>(x, w1, w2, h1, h2, y);
    cbp_finalize<<<B_N, 256, 0, stream>>>(y);
}

// Round 2
// 404.520 us; speedup vs baseline: 1.0221x; 1.0221x over previous
//
#include <hip/hip_runtime.h>

// Compact Bilinear Pooling, reformulated:
//   y_b[d] = sum_{i,j} w1[i] w2[j] (X_b X_b^T)[i,j] [ (h1[i]+h2[j]) % D == d ]
// Round 2: pre-convert x -> split-bf16 (hi/lo) planes in d_ws once (kills the
// VALU-bound redundant conversion, 32x less cvt work); signs w1/w2 applied at
// the scatter (row/col scaling of G); XCD-swizzle so each batch's 32 blocks
// share one XCD's L2 (B-panel working set 3.7MB < 4MB L2/XCD).

#define D_PROJ 16384
#define C_CH   2048
#define HW_N   196
#define KPAD   224
#define B_N    16
#define RI     64      // i-rows per block (16 per wave)
#define THREADS 256

typedef short  short8 __attribute__((ext_vector_type(8)));
typedef float  f32x4  __attribute__((ext_vector_type(4)));

static __device__ inline unsigned short f2bf(float f) {
    union { float f; unsigned u; } a; a.f = f;
    unsigned u = a.u;
    return (unsigned short)((u + 0x7FFFu + ((u >> 16) & 1u)) >> 16);  // RNE
}
static __device__ inline float bf2f(unsigned short h) {
    union { unsigned u; float f; } a; a.u = ((unsigned)h) << 16;
    return a.f;
}
static __device__ inline void cvt_split(const float (&v)[8], short8& hi, short8& lo) {
#pragma unroll
    for (int e = 0; e < 8; ++e) {
        unsigned short h = f2bf(v[e]);
        hi[e] = (short)h;
        lo[e] = (short)f2bf(v[e] - bf2f(h));
    }
}
static __device__ inline f32x4 mfma16(short8 a, short8 b, f32x4 c) {
    return __builtin_amdgcn_mfma_f32_16x16x32_bf16(a, b, c, 0, 0, 0);
}

// ---------------- pre-convert: x (f32) -> hi/lo bf16 planes, K padded to 224 ----
__global__ __launch_bounds__(256)
void cbp_convert(const float* __restrict__ x,
                 unsigned short* __restrict__ whi,
                 unsigned short* __restrict__ wlo) {
    const long long id = (long long)blockIdx.x * 256 + threadIdx.x;
    if (id >= (long long)B_N * C_CH * KPAD) return;
    const int  k   = (int)(id % KPAD);
    const long long row = id / KPAD;
    float v = (k < HW_N) ? x[row * HW_N + k] : 0.0f;
    unsigned short h = f2bf(v);
    whi[id] = h;
    wlo[id] = f2bf(v - bf2f(h));
}

// ---------------- main: Gram MFMA + count-sketch scatter into LDS histogram ----
__global__ __launch_bounds__(THREADS, 2)
void cbp_gram_scatter2(const unsigned short* __restrict__ xhi,
                       const unsigned short* __restrict__ xlo,
                       const float* __restrict__ w1f,
                       const float* __restrict__ w2f,
                       const int*   __restrict__ h1,
                       const int*   __restrict__ h2,
                       float*       __restrict__ y) {
    __shared__ float hist[D_PROJ];          // 64 KB -> 2 blocks/CU

    // bijective swizzle: batch b's 32 blocks all land on XCD b>>1 (round-robin id%8)
    const int id    = blockIdx.x;           // 0..511
    const int xcd   = id & 7;
    const int s     = id >> 3;              // 0..63
    const int b     = xcd * 2 + (s >> 5);
    const int chunk = s & 31;
    const int i0    = chunk * RI;

    const int tid  = threadIdx.x;
    const int wave = tid >> 6;
    const int lane = tid & 63;
    const int l15  = lane & 15;
    const int lgrp = lane >> 4;

    for (int t = tid; t < D_PROJ; t += THREADS) hist[t] = 0.0f;

    // ---- preload A fragments: 16 rows/wave, 7 k-steps of 32 (hi+lo) ----
    const int    irow = i0 + wave * 16 + l15;
    const size_t arow = ((size_t)b * C_CH + irow) * KPAD + lgrp * 8;
    short8 a_hi[7], a_lo[7];
#pragma unroll
    for (int ks = 0; ks < 7; ++ks) {
        a_hi[ks] = *(const short8*)(xhi + arow + ks * 32);
        a_lo[ks] = *(const short8*)(xlo + arow + ks * 32);
    }

    // per-lane output metadata: row r of this lane's 4 C-values
    int   binr[4];
    float s1r[4];
#pragma unroll
    for (int r = 0; r < 4; ++r) {
        const int ir = i0 + wave * 16 + lgrp * 4 + r;
        binr[r] = h1[ir];
        s1r[r]  = w1f[ir];
    }

    __syncthreads();                        // hist zeroed

    for (int jt = 0; jt < C_CH / 16; ++jt) {
        const int jrow = jt * 16 + l15;
        const size_t brow = ((size_t)b * C_CH + jrow) * KPAD + lgrp * 8;
        const unsigned short* ph = xhi + brow;
        const unsigned short* pl = xlo + brow;
        const float w2s = w2f[jrow];
        const int   h2j = h2[jrow];

        f32x4 acc0 = {0.f, 0.f, 0.f, 0.f};
        f32x4 acc1 = {0.f, 0.f, 0.f, 0.f};
#pragma unroll
        for (int ks = 0; ks < 7; ++ks) {
            const short8 bh = *(const short8*)(ph + ks * 32);
            const short8 bl = *(const short8*)(pl + ks * 32);
            // split-bf16: G = hi*hi + hi*lo + lo*hi (lo*lo dropped, ~2^-18)
            if (ks & 1) {
                acc1 = mfma16(a_hi[ks], bh, acc1);
                acc1 = mfma16(a_hi[ks], bl, acc1);
                acc1 = mfma16(a_lo[ks], bh, acc1);
            } else {
                acc0 = mfma16(a_hi[ks], bh, acc0);
                acc0 = mfma16(a_hi[ks], bl, acc0);
                acc0 = mfma16(a_lo[ks], bh, acc0);
            }
        }
        const f32x4 g = acc0 + acc1;
        // C/D layout (HW-verified): col = lane&15 -> j, row = (lane>>4)*4+r -> i
#pragma unroll
        for (int r = 0; r < 4; ++r) {
            int bin = binr[r] + h2j;
            if (bin >= D_PROJ) bin -= D_PROJ;
            atomicAdd(&hist[bin], g[r] * (s1r[r] * w2s));
        }
    }

    __syncthreads();
    float* yb = y + (size_t)b * D_PROJ;
    for (int t = tid; t < D_PROJ; t += THREADS)
        atomicAdd(&yb[t], hist[t]);
}

// ---------------- fallback (round-1 kernel, used if ws too small) --------------
__global__ __launch_bounds__(THREADS, 2)
void cbp_gram_scatter(const float* __restrict__ x,
                      const float* __restrict__ w1f,
                      const float* __restrict__ w2f,
                      const int*   __restrict__ h1,
                      const int*   __restrict__ h2,
                      float*       __restrict__ y) {
    __shared__ float hist[D_PROJ];
    const int b    = blockIdx.y;
    const int i0   = blockIdx.x * RI;
    const int tid  = threadIdx.x;
    const int wave = tid >> 6;
    const int lane = tid & 63;
    const int l15  = lane & 15;
    const int lgrp = lane >> 4;

    for (int t = tid; t < D_PROJ; t += THREADS) hist[t] = 0.0f;
    const float* xb = x + (size_t)b * (C_CH * HW_N);

    const int    irow = i0 + wave * 16 + l15;
    const float* xa   = xb + (size_t)irow * HW_N;
    const float  w1s  = w1f[irow];
    short8 a_hi[7], a_lo[7];
#pragma unroll
    for (int ks = 0; ks < 7; ++ks) {
        const int k0 = ks * 32 + lgrp * 8;
        float v[8];
#pragma unroll
        for (int e = 0; e < 8; ++e) {
            const int k = k0 + e;
            v[e] = (k < HW_N) ? xa[k] * w1s : 0.0f;
        }
        cvt_split(v, a_hi[ks], a_lo[ks]);
    }
    int bin1[4];
#pragma unroll
    for (int r = 0; r < 4; ++r) bin1[r] = h1[i0 + wave * 16 + lgrp * 4 + r];

    __syncthreads();

    for (int jt = 0; jt < C_CH / 16; ++jt) {
        const int    jrow = jt * 16 + l15;
        const float* xj   = xb + (size_t)jrow * HW_N;
        const float  w2s  = w2f[jrow];
        const int    h2j  = h2[jrow];
        f32x4 acc0 = {0.f, 0.f, 0.f, 0.f};
        f32x4 acc1 = {0.f, 0.f, 0.f, 0.f};
#pragma unroll
        for (int ks = 0; ks < 7; ++ks) {
            const int k0 = ks * 32 + lgrp * 8;
            float v[8];
            if (ks < 6) {
                f32x4 p0 = *(const f32x4*)(xj + k0);
                f32x4 p1 = *(const f32x4*)(xj + k0 + 4);
#pragma unroll
                for (int e = 0; e < 4; ++e) { v[e] = p0[e]; v[4 + e] = p1[e]; }
            } else {
#pragma unroll
                for (int e = 0; e < 8; ++e) {
                    const int k = k0 + e;
                    v[e] = (k < HW_N) ? xj[k] : 0.0f;
                }
            }
#pragma unroll
            for (int e = 0; e < 8; ++e) v[e] *= w2s;
            short8 bhi, blo;
            cvt_split(v, bhi, blo);
            if (ks & 1) {
                acc1 = mfma16(a_hi[ks], bhi, acc1);
                acc1 = mfma16(a_hi[ks], blo, acc1);
                acc1 = mfma16(a_lo[ks], bhi, acc1);
            } else {
                acc0 = mfma16(a_hi[ks], bhi, acc0);
                acc0 = mfma16(a_hi[ks], blo, acc0);
                acc0 = mfma16(a_lo[ks], bhi, acc0);
            }
        }
        const f32x4 g = acc0 + acc1;
#pragma unroll
        for (int r = 0; r < 4; ++r) {
            int bin = bin1[r] + h2j;
            if (bin >= D_PROJ) bin -= D_PROJ;
            atomicAdd(&hist[bin], g[r]);
        }
    }

    __syncthreads();
    float* yb = y + (size_t)b * D_PROJ;
    for (int t = tid; t < D_PROJ; t += THREADS)
        atomicAdd(&yb[t], hist[t]);
}

__global__ void cbp_finalize(float* __restrict__ y) {
    const int b   = blockIdx.x;
    const int tid = threadIdx.x;
    float* yb = y + (size_t)b * D_PROJ;
    __shared__ float partial[4];

    float ssum = 0.f;
    for (int t = tid; t < D_PROJ; t += 256) {
        float v = yb[t];
        float s = copysignf(sqrtf(fabsf(v) + 1e-8f), v);
        yb[t] = s;
        ssum += s * s;
    }
    const int lane = tid & 63, wv = tid >> 6;
#pragma unroll
    for (int off = 32; off > 0; off >>= 1) ssum += __shfl_down(ssum, off, 64);
    if (lane == 0) partial[wv] = ssum;
    __syncthreads();
    const float total = partial[0] + partial[1] + partial[2] + partial[3];
    const float inv = 1.0f / sqrtf(total + 1e-8f);
    for (int t = tid; t < D_PROJ; t += 256) yb[t] *= inv;
}

extern "C" void kernel_launch(void* const* d_in, const int* in_sizes, int n_in,
                              void* d_out, int out_size, void* d_ws, size_t ws_size,
                              hipStream_t stream) {
    const float* x  = (const float*)d_in[0];
    const float* w1 = (const float*)d_in[1];
    const float* w2 = (const float*)d_in[2];
    const int*   h1 = (const int*)d_in[3];
    const int*   h2 = (const int*)d_in[4];
    float* y = (float*)d_out;

    hipMemsetAsync(y, 0, (size_t)B_N * D_PROJ * sizeof(float), stream);

    const size_t plane = (size_t)B_N * C_CH * KPAD;          // elements per plane
    const size_t need  = plane * 2 * sizeof(unsigned short); // 29.36 MB

    if (ws_size >= need) {
        unsigned short* whi = (unsigned short*)d_ws;
        unsigned short* wlo = whi + plane;
        const long long tot = (long long)plane;
        cbp_convert<<<(int)((tot + 255) / 256), 256, 0, stream>>>(x, whi, wlo);
        cbp_gram_scatter2<<<(C_CH / RI) * B_N, THREADS, 0, stream>>>(
            whi, wlo, w1, w2, h1, h2, y);
    } else {
        dim3 grid(C_CH / RI, B_N);
        cbp_gram_scatter<<<grid, THREADS, 0, stream>>>(x, w1, w2, h1, h2, y);
    }
    cbp_finalize<<<B_N, 256, 0, stream>>>(y);
}